// Round 1
// baseline (290.235 us; speedup 1.0000x reference)
//
#include <hip/hip_runtime.h>

// ---------------------------------------------------------------------------
// AttentionFlow: linearized per-node-table formulation.
//   hc   = tanh(hidden_con @ W_h + b_h)                      (80000 x 64)
//   hu   = tanh(hidden_uncon @ W_hlg + b_hlg)                (50000 x 64)
//   Ahc  = hc @ [Wl0 | Wl1_top | Wr0 | Wr1_top]              (80000 x 256)
//   Ahu  = hu @ [Wl0 | Wl1_top | Wr0 | Wr1_top]              (50000 x 256)
//   qv   = tanh(qhe@W_hlg+b) + tanh(qre@W_rlg+b)             (32 x 64)
//   ql1b = qv @ Wl1_bot + bl1 ; qr1b = qv @ Wr1_bot + br1    (32 x 64)
// per edge e:
//   l0 = tanh(Ahc[inv[e2vi]][0:64]   + Ahu[vi][0:64]   + bl0)
//   l1 = tanh(Ahc[inv[e2vi]][64:128] + Ahu[vi][64:128] + ql1b[eg])
//   r0 = tanh(Ahc[inv[e2vj]][128:192]+ Ahu[vj][128:192]+ br0)
//   r1 = tanh(Ahc[inv[e2vj]][192:256]+ Ahu[vj][192:256]+ qr1b[eg])
//   logit = l0.r0 + l1.r1 ; segment softmax over seg_vi ; * edges_y
//   out[eg, vj] += node_attention[eg, vi] * trans
// ---------------------------------------------------------------------------

__device__ __forceinline__ float fast_tanh(float x) {
    // tanh(x) = 1 - 2/(exp(2x)+1); exact at +-inf, ~1e-7 rel error
    float e = __expf(2.0f * x);
    return 1.0f - 2.0f / (e + 1.0f);
}

__device__ __forceinline__ unsigned int fenc(float f) {
    unsigned int u = __float_as_uint(f);
    return (u & 0x80000000u) ? ~u : (u | 0x80000000u);
}
__device__ __forceinline__ float fdec(unsigned int e) {
    return __uint_as_float((e & 0x80000000u) ? (e ^ 0x80000000u) : ~e);
}

__global__ void k_scatter_inv(const int* __restrict__ new_idx, int* __restrict__ inv, int M) {
    int i = blockIdx.x * blockDim.x + threadIdx.x;
    if (i < M) inv[new_idx[i]] = i;
}

// 32 blocks x 64 threads: q-side tiny precompute
__global__ void k_q(const float* __restrict__ qhe, const float* __restrict__ qre,
                    const float* __restrict__ W_hlg, const float* __restrict__ b_hlg,
                    const float* __restrict__ W_rlg, const float* __restrict__ b_rlg,
                    const float* __restrict__ Wl1, const float* __restrict__ bl1,
                    const float* __restrict__ Wr1, const float* __restrict__ br1,
                    float* __restrict__ ql1b, float* __restrict__ qr1b) {
    __shared__ float qv_s[64];
    int b = blockIdx.x, d = threadIdx.x;
    float ah = 0.f, ar = 0.f;
    for (int k = 0; k < 256; ++k) {
        ah += qhe[b * 256 + k] * W_hlg[k * 64 + d];
        ar += qre[b * 256 + k] * W_rlg[k * 64 + d];
    }
    qv_s[d] = fast_tanh(ah + b_hlg[d]) + fast_tanh(ar + b_rlg[d]);
    __syncthreads();
    float a1 = 0.f, a2 = 0.f;
    for (int k = 0; k < 64; ++k) {
        float v = qv_s[k];
        a1 += v * Wl1[(64 + k) * 64 + d];
        a2 += v * Wr1[(64 + k) * 64 + d];
    }
    ql1b[b * 64 + d] = a1 + bl1[d];
    qr1b[b * 64 + d] = a2 + br1[d];
}

// hidden_con -> Ahc. 256 threads = 4 waves, 8 rows/wave -> 32 rows/block.
__global__ void k_hc(const float* __restrict__ hidden_con,
                     const float* __restrict__ W_h, const float* __restrict__ b_h,
                     const float* __restrict__ Wl0, const float* __restrict__ Wl1,
                     const float* __restrict__ Wr0, const float* __restrict__ Wr1,
                     float* __restrict__ Ahc, int M) {
    __shared__ float xs[32][64];
    __shared__ float hs[32][64];
    int t = threadIdx.x;
    int base = blockIdx.x * 32;
    #pragma unroll
    for (int i = 0; i < 8; ++i) {
        int idx = i * 256 + t;
        int r = idx >> 6, c = idx & 63;
        xs[r][c] = (base + r < M) ? hidden_con[(size_t)(base + r) * 64 + c] : 0.f;
    }
    __syncthreads();
    int w = t >> 6, d = t & 63;
    int r0 = w * 8;
    float acc[8];
    #pragma unroll
    for (int j = 0; j < 8; ++j) acc[j] = 0.f;
    for (int k = 0; k < 64; ++k) {
        float wv = W_h[k * 64 + d];
        #pragma unroll
        for (int j = 0; j < 8; ++j) acc[j] += xs[r0 + j][k] * wv;
    }
    float bh = b_h[d];
    #pragma unroll
    for (int j = 0; j < 8; ++j) hs[r0 + j][d] = fast_tanh(acc[j] + bh);
    __syncthreads();
    float a0[8], a1[8], a2[8], a3[8];
    #pragma unroll
    for (int j = 0; j < 8; ++j) { a0[j] = a1[j] = a2[j] = a3[j] = 0.f; }
    for (int k = 0; k < 64; ++k) {
        float w0 = Wl0[k * 64 + d];
        float w1 = Wl1[k * 64 + d];   // top half of Wl1 (rows 0..63)
        float w2 = Wr0[k * 64 + d];
        float w3 = Wr1[k * 64 + d];
        #pragma unroll
        for (int j = 0; j < 8; ++j) {
            float x = hs[r0 + j][k];
            a0[j] += x * w0; a1[j] += x * w1; a2[j] += x * w2; a3[j] += x * w3;
        }
    }
    #pragma unroll
    for (int j = 0; j < 8; ++j) {
        int r = base + r0 + j;
        if (r < M) {
            size_t o = (size_t)r * 256;
            Ahc[o + d]       = a0[j];
            Ahc[o + 64 + d]  = a1[j];
            Ahc[o + 128 + d] = a2[j];
            Ahc[o + 192 + d] = a3[j];
        }
    }
}

// hidden_uncon -> Ahu (stage1 K=256). 32 rows/block.
__global__ void k_hu(const float* __restrict__ hidden_uncon,
                     const float* __restrict__ W_hlg, const float* __restrict__ b_hlg,
                     const float* __restrict__ Wl0, const float* __restrict__ Wl1,
                     const float* __restrict__ Wr0, const float* __restrict__ Wr1,
                     float* __restrict__ Ahu, int N) {
    __shared__ float xs[32][256];
    __shared__ float hs[32][64];
    int t = threadIdx.x;
    int base = blockIdx.x * 32;
    #pragma unroll
    for (int i = 0; i < 32; ++i) {
        int idx = i * 256 + t;
        int r = idx >> 8, c = idx & 255;
        xs[r][c] = (base + r < N) ? hidden_uncon[(size_t)(base + r) * 256 + c] : 0.f;
    }
    __syncthreads();
    int w = t >> 6, d = t & 63;
    int r0 = w * 8;
    float acc[8];
    #pragma unroll
    for (int j = 0; j < 8; ++j) acc[j] = 0.f;
    for (int k = 0; k < 256; ++k) {
        float wv = W_hlg[k * 64 + d];
        #pragma unroll
        for (int j = 0; j < 8; ++j) acc[j] += xs[r0 + j][k] * wv;
    }
    float bh = b_hlg[d];
    __shared__ float dummy_sync;
    (void)dummy_sync;
    #pragma unroll
    for (int j = 0; j < 8; ++j) hs[r0 + j][d] = fast_tanh(acc[j] + bh);
    __syncthreads();
    float a0[8], a1[8], a2[8], a3[8];
    #pragma unroll
    for (int j = 0; j < 8; ++j) { a0[j] = a1[j] = a2[j] = a3[j] = 0.f; }
    for (int k = 0; k < 64; ++k) {
        float w0 = Wl0[k * 64 + d];
        float w1 = Wl1[k * 64 + d];
        float w2 = Wr0[k * 64 + d];
        float w3 = Wr1[k * 64 + d];
        #pragma unroll
        for (int j = 0; j < 8; ++j) {
            float x = hs[r0 + j][k];
            a0[j] += x * w0; a1[j] += x * w1; a2[j] += x * w2; a3[j] += x * w3;
        }
    }
    #pragma unroll
    for (int j = 0; j < 8; ++j) {
        int r = base + r0 + j;
        if (r < N) {
            size_t o = (size_t)r * 256;
            Ahu[o + d]       = a0[j];
            Ahu[o + 64 + d]  = a1[j];
            Ahu[o + 128 + d] = a2[j];
            Ahu[o + 192 + d] = a3[j];
        }
    }
}

// one wave per edge: gather 8x256B, 4 tanh vectors, dot, segment max
__global__ void k_edge(const int* __restrict__ se, const int* __restrict__ inv,
                       const float* __restrict__ Ahc, const float* __restrict__ Ahu,
                       const float* __restrict__ bl0, const float* __restrict__ br0,
                       const float* __restrict__ ql1b, const float* __restrict__ qr1b,
                       float* __restrict__ logits, unsigned int* __restrict__ pmax,
                       int E) {
    int wid = (int)((blockIdx.x * blockDim.x + threadIdx.x) >> 6);
    int d = threadIdx.x & 63;
    if (wid >= E) return;
    const int* row = se + (size_t)wid * 8;
    int eg = row[0], vi = row[1], vj = row[2], seg = row[4], e2vi = row[6], e2vj = row[7];
    int ii = inv[e2vi], ij = inv[e2vj];
    float a0 = 0.f, a1 = 0.f, c2 = 0.f, c3 = 0.f;
    if (ii >= 0) {
        const float* p = Ahc + (size_t)ii * 256;
        a0 = p[d]; a1 = p[64 + d];
    }
    if (ij >= 0) {
        const float* p = Ahc + (size_t)ij * 256;
        c2 = p[128 + d]; c3 = p[192 + d];
    }
    const float* pu = Ahu + (size_t)vi * 256;
    const float* pv = Ahu + (size_t)vj * 256;
    float l0 = fast_tanh(a0 + pu[d] + bl0[d]);
    float l1 = fast_tanh(a1 + pu[64 + d] + ql1b[eg * 64 + d]);
    float r0 = fast_tanh(c2 + pv[128 + d] + br0[d]);
    float r1 = fast_tanh(c3 + pv[192 + d] + qr1b[eg * 64 + d]);
    float p = l0 * r0 + l1 * r1;
    #pragma unroll
    for (int off = 32; off; off >>= 1) p += __shfl_xor(p, off);
    if (d == 0) {
        logits[wid] = p;
        atomicMax(&pmax[seg], fenc(p));
    }
}

__global__ void k_exp(const int* __restrict__ se, const float* __restrict__ logits,
                      const unsigned int* __restrict__ pmax, float* __restrict__ trans,
                      float* __restrict__ psum, int E) {
    int e = blockIdx.x * blockDim.x + threadIdx.x;
    if (e >= E) return;
    int seg = se[(size_t)e * 8 + 4];
    float x = __expf(logits[e] - fdec(pmax[seg]));
    trans[e] = x;
    atomicAdd(&psum[seg], x);
}

__global__ void k_final(const int* __restrict__ se, const float* __restrict__ trans,
                        const float* __restrict__ psum, const float* __restrict__ ey,
                        const float* __restrict__ natt, float* __restrict__ out,
                        int E, int N) {
    int e = blockIdx.x * blockDim.x + threadIdx.x;
    if (e >= E) return;
    const int* row = se + (size_t)e * 8;
    int eg = row[0], vi = row[1], vj = row[2], seg = row[4];
    float t = trans[e] / psum[seg] * ey[e] * natt[(size_t)eg * N + vi];
    atomicAdd(&out[(size_t)eg * N + vj], t);
}

extern "C" void kernel_launch(void* const* d_in, const int* in_sizes, int n_in,
                              void* d_out, int out_size, void* d_ws, size_t ws_size,
                              hipStream_t stream) {
    const float* natt  = (const float*)d_in[0];
    const float* ey    = (const float*)d_in[1];
    const float* h_unc = (const float*)d_in[2];
    const float* h_con = (const float*)d_in[3];
    const float* qhe   = (const float*)d_in[4];
    const float* qre   = (const float*)d_in[5];
    const float* W_h   = (const float*)d_in[6];
    const float* b_h   = (const float*)d_in[7];
    const float* W_hlg = (const float*)d_in[8];
    const float* b_hlg = (const float*)d_in[9];
    const float* W_rlg = (const float*)d_in[10];
    const float* b_rlg = (const float*)d_in[11];
    const float* Wl0   = (const float*)d_in[12];
    const float* bl0   = (const float*)d_in[13];
    const float* Wr0   = (const float*)d_in[14];
    const float* br0   = (const float*)d_in[15];
    const float* Wl1   = (const float*)d_in[16];
    const float* bl1   = (const float*)d_in[17];
    const float* Wr1   = (const float*)d_in[18];
    const float* br1   = (const float*)d_in[19];
    const int* se      = (const int*)d_in[20];
    const int* new_idx = (const int*)d_in[21];

    const int B     = 32;
    const int N     = in_sizes[0] / B;    // 50000
    const int E     = in_sizes[20] / 8;   // 200000
    const int M_MEM = in_sizes[21];       // 80000
    const int M_ALL = 100000;
    const int NSEG  = 80000;

    char* ws = (char*)d_ws;
    size_t off = 0;
    float* Ahc = (float*)(ws + off);        off += (size_t)M_MEM * 256 * 4;
    float* Ahu = (float*)(ws + off);        off += (size_t)N * 256 * 4;
    int* inv = (int*)(ws + off);            off += (size_t)M_ALL * 4;
    float* logits = (float*)(ws + off);     off += (size_t)E * 4;
    float* trans = (float*)(ws + off);      off += (size_t)E * 4;
    unsigned int* pmax = (unsigned int*)(ws + off); off += (size_t)NSEG * 4;
    float* psum = (float*)(ws + off);       off += (size_t)NSEG * 4;
    float* ql1b = (float*)(ws + off);       off += (size_t)B * 64 * 4;
    float* qr1b = (float*)(ws + off);       off += (size_t)B * 64 * 4;

    hipMemsetAsync(d_out, 0, (size_t)out_size * 4, stream);
    hipMemsetAsync(inv, 0xFF, (size_t)M_ALL * 4, stream);           // -1
    hipMemsetAsync(pmax, 0, (size_t)NSEG * 8, stream);              // pmax(enc) + psum

    k_scatter_inv<<<(M_MEM + 255) / 256, 256, 0, stream>>>(new_idx, inv, M_MEM);
    k_q<<<B, 64, 0, stream>>>(qhe, qre, W_hlg, b_hlg, W_rlg, b_rlg,
                              Wl1, bl1, Wr1, br1, ql1b, qr1b);
    k_hc<<<(M_MEM + 31) / 32, 256, 0, stream>>>(h_con, W_h, b_h, Wl0, Wl1, Wr0, Wr1, Ahc, M_MEM);
    k_hu<<<(N + 31) / 32, 256, 0, stream>>>(h_unc, W_hlg, b_hlg, Wl0, Wl1, Wr0, Wr1, Ahu, N);
    k_edge<<<(E + 3) / 4, 256, 0, stream>>>(se, inv, Ahc, Ahu, bl0, br0, ql1b, qr1b,
                                            logits, pmax, E);
    k_exp<<<(E + 255) / 256, 256, 0, stream>>>(se, logits, pmax, trans, psum, E);
    k_final<<<(E + 255) / 256, 256, 0, stream>>>(se, trans, psum, ey, natt, (float*)d_out, E, N);
}